// Round 1
// baseline (606.032 us; speedup 1.0000x reference)
//
#include <hip/hip_runtime.h>
#include <cstdint>

#define B_ 16
#define N_ 2048
#define D_ 256
#define EPS_ 1e-9f

typedef float f4 __attribute__((ext_vector_type(4)));
typedef __attribute__((ext_vector_type(8))) short short8;

__device__ inline unsigned short f2bf(float x){
  unsigned int u = __float_as_uint(x);
  u = (u + 0x7fffu + ((u >> 16) & 1u)) >> 16;
  return (unsigned short)u;
}

// one wave per row of 256: fp32 norm + bf16 conversion
__global__ __launch_bounds__(256) void prep_kernel(const float* __restrict__ src,
    unsigned short* __restrict__ dst, float* __restrict__ norms){
  int gw = (blockIdx.x * blockDim.x + threadIdx.x) >> 6;
  int lane = threadIdx.x & 63;
  const float4 v = ((const float4*)(src + (size_t)gw * D_))[lane];
  float s = v.x*v.x + v.y*v.y + v.z*v.z + v.w*v.w;
  #pragma unroll
  for (int off = 32; off >= 1; off >>= 1) s += __shfl_xor(s, off);
  if (lane == 0) norms[gw] = s;
  ushort4 o; o.x = f2bf(v.x); o.y = f2bf(v.y); o.z = f2bf(v.z); o.w = f2bf(v.w);
  ((ushort4*)(dst + (size_t)gw * D_))[lane] = o;
}

__global__ __launch_bounds__(256) void init_state(float* __restrict__ cost0,
    float* __restrict__ currency, int* __restrict__ dmin){
  int i = blockIdx.x * 256 + threadIdx.x;
  if (i < B_ * N_){ cost0[i] = 1.f; currency[i] = 1.f; }
  if (i < B_) dmin[i] = 0x7f7fffff;  // FLT_MAX bits
}

// pwdist[b][n][m] = pn[n] + ln[m] - 2 * dot(preds[n], labels[m]) via bf16 MFMA
// 128x128 tile, 4 waves, each wave 64x64 (4x4 MFMA 16x16x32). XOR-swizzled LDS.
__global__ __launch_bounds__(256) void gemm_pwdist(
    const unsigned short* __restrict__ pa, const unsigned short* __restrict__ pbm,
    const float* __restrict__ pn, const float* __restrict__ ln,
    float* __restrict__ pwd, int* __restrict__ dmin, int b0)
{
  int lb = blockIdx.z, b = b0 + lb;
  const unsigned short* A  = pa  + (size_t)b * N_ * D_;
  const unsigned short* Bm = pbm + (size_t)b * N_ * D_;
  int tm = blockIdx.x * 128, tn = blockIdx.y * 128;
  __shared__ __align__(16) unsigned short As[128 * 64];
  __shared__ __align__(16) unsigned short Bs[128 * 64];
  int tid = threadIdx.x, lane = tid & 63, w = tid >> 6;
  int wm = (w >> 1) * 64, wn = (w & 1) * 64;
  int quad = lane >> 4, l15 = lane & 15;
  f4 acc[4][4];
  #pragma unroll
  for (int i = 0; i < 4; i++)
    #pragma unroll
    for (int j = 0; j < 4; j++) acc[i][j] = (f4)0.f;
  int cch = tid & 7, r0 = tid >> 3;
  for (int kt = 0; kt < D_; kt += 64){
    #pragma unroll
    for (int p = 0; p < 4; p++){
      int r = r0 + p * 32;
      *(uint4*)(&As[r * 64 + ((cch ^ (r & 7)) * 8)]) =
          *(const uint4*)(&A[(size_t)(tm + r) * D_ + kt + cch * 8]);
      *(uint4*)(&Bs[r * 64 + ((cch ^ (r & 7)) * 8)]) =
          *(const uint4*)(&Bm[(size_t)(tn + r) * D_ + kt + cch * 8]);
    }
    __syncthreads();
    #pragma unroll
    for (int ks = 0; ks < 2; ks++){
      short8 af[4], bf[4];
      int j = ks * 4 + quad;
      #pragma unroll
      for (int i = 0; i < 4; i++){
        int ra = wm + i * 16 + l15;
        af[i] = *(const short8*)(&As[ra * 64 + ((j ^ (ra & 7)) * 8)]);
        int rb = wn + i * 16 + l15;
        bf[i] = *(const short8*)(&Bs[rb * 64 + ((j ^ (rb & 7)) * 8)]);
      }
      #pragma unroll
      for (int i = 0; i < 4; i++)
        #pragma unroll
        for (int jj = 0; jj < 4; jj++)
          acc[i][jj] = __builtin_amdgcn_mfma_f32_16x16x32_bf16(af[i], bf[jj], acc[i][jj], 0, 0, 0);
    }
    __syncthreads();
  }
  // epilogue: C/D layout col = lane&15, row = quad*4 + reg
  float mind = 3.4e38f;
  #pragma unroll
  for (int i = 0; i < 4; i++){
    int grb = tm + wm + i * 16 + quad * 4;
    #pragma unroll
    for (int jj = 0; jj < 4; jj++){
      int gc = tn + wn + jj * 16 + l15;
      float lnv = ln[(size_t)b * N_ + gc];
      #pragma unroll
      for (int reg = 0; reg < 4; reg++){
        float v = pn[(size_t)b * N_ + grb + reg] + lnv - 2.f * acc[i][jj][reg];
        pwd[((size_t)lb * N_ + grb + reg) * N_ + gc] = v;
        mind = fminf(mind, v);
      }
    }
  }
  #pragma unroll
  for (int off = 32; off >= 1; off >>= 1) mind = fminf(mind, __shfl_xor(mind, off));
  if (lane == 0) atomicMin(&dmin[b], __float_as_int(fmaxf(mind, 0.f)));
}

// Pass A: s = exp(ef*d)*cost; rowsum -> alpha = currency/(rowsum+eps);
// col partial sums of s*alpha -> global colsum (block-combined in LDS).
__global__ __launch_bounds__(256) void iter_rows(
    const float* __restrict__ pwd, const float* __restrict__ cost,
    const float* __restrict__ currency, float* __restrict__ alpha,
    float* __restrict__ colsum, const int* __restrict__ dmin,
    float ef, int b0)
{
  int lb = blockIdx.y, b = b0 + lb;
  if (ef != 0.f && ef * __int_as_float(dmin[b]) < -87.f) return;  // provable no-op
  int tid = threadIdx.x, lane = tid & 63, w = tid >> 6;
  const float4* costv = (const float4*)(cost + (size_t)b * N_);
  f4 colacc[8];
  #pragma unroll
  for (int j = 0; j < 8; j++) colacc[j] = (f4)0.f;
  int row0 = blockIdx.x * 16 + w * 4;
  for (int q = 0; q < 4; q++){
    int r = row0 + q;
    const float4* drow = (const float4*)(pwd + ((size_t)lb * N_ + r) * N_);
    f4 sv[8];
    float ls = 0.f;
    #pragma unroll
    for (int j = 0; j < 8; j++){
      float4 d = drow[j * 64 + lane];
      float4 c = costv[j * 64 + lane];
      f4 s;
      s[0] = __expf(ef * d.x) * c.x; s[1] = __expf(ef * d.y) * c.y;
      s[2] = __expf(ef * d.z) * c.z; s[3] = __expf(ef * d.w) * c.w;
      sv[j] = s;
      ls += s[0] + s[1] + s[2] + s[3];
    }
    #pragma unroll
    for (int off = 32; off >= 1; off >>= 1) ls += __shfl_xor(ls, off);
    float a = currency[(size_t)b * N_ + r] / (ls + EPS_);
    if (lane == 0) alpha[(size_t)b * N_ + r] = a;
    #pragma unroll
    for (int j = 0; j < 8; j++) colacc[j] += sv[j] * a;
  }
  __shared__ __align__(16) float csum[4][2048];
  f4* dst = (f4*)&csum[w][0];
  #pragma unroll
  for (int j = 0; j < 8; j++) dst[j * 64 + lane] = colacc[j];
  __syncthreads();
  #pragma unroll
  for (int k = 0; k < 8; k++){
    int col = tid + k * 256;
    float v = csum[0][col] + csum[1][col] + csum[2][col] + csum[3][col];
    atomicAdd(&colsum[(size_t)b * N_ + col], v);
  }
}

// tiny per-column: bid_wt = min(cost/(colsum+eps),1); cost_new = max(cost - bw*colsum, 0)
__global__ __launch_bounds__(256) void iter_cols(
    const float* __restrict__ colsum, const float* __restrict__ cost_old,
    float* __restrict__ cost_new, float* __restrict__ bidwt, int b0)
{
  int idx = blockIdx.x * 256 + threadIdx.x;
  int b = b0 + (idx >> 11);
  int n = idx & 2047;
  size_t o = (size_t)b * N_ + n;
  float cs = colsum[o], c = cost_old[o];
  float bw = fminf(c / (cs + EPS_), 1.f);
  bidwt[o] = bw;
  cost_new[o] = fmaxf(c - bw * cs, 0.f);
}

// Pass B: bids = s*alpha*bid_wt; accumulate sum(bids*d) into out; update currency.
__global__ __launch_bounds__(256) void iter_finish(
    const float* __restrict__ pwd, const float* __restrict__ cost,
    float* __restrict__ currency, const float* __restrict__ alpha,
    const float* __restrict__ bidwt, const int* __restrict__ dmin,
    float ef, int b0, float* __restrict__ outacc)
{
  int lb = blockIdx.y, b = b0 + lb;
  if (ef != 0.f && ef * __int_as_float(dmin[b]) < -87.f) return;
  int tid = threadIdx.x, lane = tid & 63, w = tid >> 6;
  const float4* costv = (const float4*)(cost + (size_t)b * N_);
  const float4* bwv = (const float4*)(bidwt + (size_t)b * N_);
  int row0 = blockIdx.x * 16 + w * 4;
  float contrib = 0.f;
  for (int q = 0; q < 4; q++){
    int r = row0 + q;
    const float4* drow = (const float4*)(pwd + ((size_t)lb * N_ + r) * N_);
    float a = alpha[(size_t)b * N_ + r];
    float rbsum = 0.f;
    #pragma unroll
    for (int j = 0; j < 8; j++){
      float4 d = drow[j * 64 + lane];
      float4 c = costv[j * 64 + lane];
      float4 ww = bwv[j * 64 + lane];
      float b0v = __expf(ef * d.x) * c.x * a * ww.x;
      float b1v = __expf(ef * d.y) * c.y * a * ww.y;
      float b2v = __expf(ef * d.z) * c.z * a * ww.z;
      float b3v = __expf(ef * d.w) * c.w * a * ww.w;
      rbsum  += b0v + b1v + b2v + b3v;
      contrib += b0v * d.x + b1v * d.y + b2v * d.z + b3v * d.w;
    }
    #pragma unroll
    for (int off = 32; off >= 1; off >>= 1) rbsum += __shfl_xor(rbsum, off);
    if (lane == 0){
      size_t o = (size_t)b * N_ + r;
      currency[o] = fmaxf(currency[o] - rbsum, 0.f);
    }
  }
  #pragma unroll
  for (int off = 32; off >= 1; off >>= 1) contrib += __shfl_xor(contrib, off);
  __shared__ float bs[4];
  if (lane == 0) bs[w] = contrib;
  __syncthreads();
  if (tid == 0) atomicAdd(outacc, bs[0] + bs[1] + bs[2] + bs[3]);
}

extern "C" void kernel_launch(void* const* d_in, const int* in_sizes, int n_in,
                              void* d_out, int out_size, void* d_ws, size_t ws_size,
                              hipStream_t stream)
{
  const float* preds  = (const float*)d_in[0];
  const float* labels = (const float*)d_in[1];
  float* out = (float*)d_out;
  char* ws = (char*)d_ws;
  const size_t BN = (size_t)B_ * N_;
  size_t off = 0;
  float* cost0    = (float*)(ws + off); off += BN * 4;
  float* cost1    = (float*)(ws + off); off += BN * 4;
  float* currency = (float*)(ws + off); off += BN * 4;
  float* alpha    = (float*)(ws + off); off += BN * 4;
  float* colsum   = (float*)(ws + off); off += BN * 4;
  float* bidwt    = (float*)(ws + off); off += BN * 4;
  float* pn       = (float*)(ws + off); off += BN * 4;
  float* ln       = (float*)(ws + off); off += BN * 4;
  int*   dmin     = (int*)(ws + off);   off += 256;
  unsigned short* pabf = (unsigned short*)(ws + off); off += BN * D_ * 2;
  unsigned short* pbbf = (unsigned short*)(ws + off); off += BN * D_ * 2;
  const size_t perb = (size_t)N_ * N_ * 4;
  int maxcb = 1;
  if (ws_size > off + perb) maxcb = (int)((ws_size - off) / perb);
  if (maxcb < 1) maxcb = 1;
  if (maxcb > B_) maxcb = B_;
  float* pwd = (float*)(ws + off);

  hipMemsetAsync(d_out, 0, sizeof(float), stream);
  init_state<<<dim3((unsigned)((BN + 255) / 256)), 256, 0, stream>>>(cost0, currency, dmin);
  prep_kernel<<<dim3((unsigned)(BN / 4)), 256, 0, stream>>>(preds, pabf, pn);
  prep_kernel<<<dim3((unsigned)(BN / 4)), 256, 0, stream>>>(labels, pbbf, ln);

  const float EF[7] = {-256.f, -64.f, -16.f, -4.f, -1.f, -0.25f, 0.f};
  for (int b0 = 0; b0 < B_; b0 += maxcb){
    int cb = (B_ - b0 < maxcb) ? (B_ - b0) : maxcb;
    gemm_pwdist<<<dim3(16, 16, cb), 256, 0, stream>>>(pabf, pbbf, pn, ln, pwd, dmin, b0);
    for (int it = 0; it < 7; it++){
      float* cro = (it & 1) ? cost1 : cost0;
      float* cwn = (it & 1) ? cost0 : cost1;
      hipMemsetAsync(colsum + (size_t)b0 * N_, 0, (size_t)cb * N_ * 4, stream);
      iter_rows<<<dim3(128, cb), 256, 0, stream>>>(pwd, cro, currency, alpha, colsum, dmin, EF[it], b0);
      iter_cols<<<dim3(cb * 8), 256, 0, stream>>>(colsum, cro, cwn, bidwt, b0);
      iter_finish<<<dim3(128, cb), 256, 0, stream>>>(pwd, cro, currency, alpha, bidwt, dmin, EF[it], b0, out);
    }
  }
}

// Round 2
// 320.802 us; speedup vs baseline: 1.8891x; 1.8891x over previous
//
#include <hip/hip_runtime.h>
#include <cstdint>

#define B_ 16
#define N_ 2048
#define D_ 256
#define EPS_ 1e-9f

typedef float f4 __attribute__((ext_vector_type(4)));
typedef __attribute__((ext_vector_type(8))) short short8;

__device__ inline unsigned short f2bf(float x){
  unsigned int u = __float_as_uint(x);
  u = (u + 0x7fffu + ((u >> 16) & 1u)) >> 16;
  return (unsigned short)u;
}
__device__ inline float bf2f(unsigned short u){
  return __uint_as_float(((unsigned int)u) << 16);
}

__device__ float blockReduceSum(float x, float* red){
  int tid = threadIdx.x;
  red[tid] = x; __syncthreads();
  #pragma unroll
  for (int off = 128; off > 0; off >>= 1){
    if (tid < off) red[tid] += red[tid + off];
    __syncthreads();
  }
  float r = red[0]; __syncthreads();
  return r;
}

// one wave per row of 256: fp32 norm + bf16 conversion
__global__ __launch_bounds__(256) void prep_kernel(const float* __restrict__ src,
    unsigned short* __restrict__ dst, float* __restrict__ norms){
  int gw = (blockIdx.x * blockDim.x + threadIdx.x) >> 6;
  int lane = threadIdx.x & 63;
  const float4 v = ((const float4*)(src + (size_t)gw * D_))[lane];
  float s = v.x*v.x + v.y*v.y + v.z*v.z + v.w*v.w;
  #pragma unroll
  for (int off = 32; off >= 1; off >>= 1) s += __shfl_xor(s, off);
  if (lane == 0) norms[gw] = s;
  ushort4 o; o.x = f2bf(v.x); o.y = f2bf(v.y); o.z = f2bf(v.z); o.w = f2bf(v.w);
  ((ushort4*)(dst + (size_t)gw * D_))[lane] = o;
}

__global__ __launch_bounds__(256) void init_state(float* __restrict__ cost,
    float* __restrict__ currency, int* __restrict__ dmin,
    float* __restrict__ PL, float* __restrict__ scal){
  int i = blockIdx.x * 256 + threadIdx.x;
  if (i < B_ * N_){ cost[i] = 1.f; currency[i] = 1.f; }
  if (i < 2 * B_ * D_) PL[i] = 0.f;
  if (i < B_ * 4) scal[i] = 0.f;
  if (i < B_) dmin[i] = 0x7f7fffff;  // FLT_MAX bits
}

// d[b][n][m] = pn[n] + ln[m] - 2*dot via bf16 MFMA; NO stores — only per-batch min.
__global__ __launch_bounds__(256) void gemm_minmax(
    const unsigned short* __restrict__ pa, const unsigned short* __restrict__ pbm,
    const float* __restrict__ pn, const float* __restrict__ ln,
    int* __restrict__ dmin)
{
  int b = blockIdx.z;
  const unsigned short* A  = pa  + (size_t)b * N_ * D_;
  const unsigned short* Bm = pbm + (size_t)b * N_ * D_;
  int tm = blockIdx.x * 128, tn = blockIdx.y * 128;
  __shared__ __align__(16) unsigned short As[128 * 64];
  __shared__ __align__(16) unsigned short Bs[128 * 64];
  int tid = threadIdx.x, lane = tid & 63, w = tid >> 6;
  int wm = (w >> 1) * 64, wn = (w & 1) * 64;
  int quad = lane >> 4, l15 = lane & 15;
  f4 acc[4][4];
  #pragma unroll
  for (int i = 0; i < 4; i++)
    #pragma unroll
    for (int j = 0; j < 4; j++) acc[i][j] = (f4)0.f;
  int cch = tid & 7, r0 = tid >> 3;
  for (int kt = 0; kt < D_; kt += 64){
    #pragma unroll
    for (int p = 0; p < 4; p++){
      int r = r0 + p * 32;
      *(uint4*)(&As[r * 64 + ((cch ^ (r & 7)) * 8)]) =
          *(const uint4*)(&A[(size_t)(tm + r) * D_ + kt + cch * 8]);
      *(uint4*)(&Bs[r * 64 + ((cch ^ (r & 7)) * 8)]) =
          *(const uint4*)(&Bm[(size_t)(tn + r) * D_ + kt + cch * 8]);
    }
    __syncthreads();
    #pragma unroll
    for (int ks = 0; ks < 2; ks++){
      short8 af[4], bf[4];
      int j = ks * 4 + quad;
      #pragma unroll
      for (int i = 0; i < 4; i++){
        int ra = wm + i * 16 + l15;
        af[i] = *(const short8*)(&As[ra * 64 + ((j ^ (ra & 7)) * 8)]);
        int rb = wn + i * 16 + l15;
        bf[i] = *(const short8*)(&Bs[rb * 64 + ((j ^ (rb & 7)) * 8)]);
      }
      #pragma unroll
      for (int i = 0; i < 4; i++)
        #pragma unroll
        for (int jj = 0; jj < 4; jj++)
          acc[i][jj] = __builtin_amdgcn_mfma_f32_16x16x32_bf16(af[i], bf[jj], acc[i][jj], 0, 0, 0);
    }
    __syncthreads();
  }
  // epilogue: C/D layout col = lane&15, row = quad*4 + reg — min only, no stores
  float mind = 3.4e38f;
  #pragma unroll
  for (int i = 0; i < 4; i++){
    int grb = tm + wm + i * 16 + quad * 4;
    #pragma unroll
    for (int jj = 0; jj < 4; jj++){
      int gc = tn + wn + jj * 16 + l15;
      float lnv = ln[(size_t)b * N_ + gc];
      #pragma unroll
      for (int reg = 0; reg < 4; reg++){
        float v = pn[(size_t)b * N_ + grb + reg] + lnv - 2.f * acc[i][jj][reg];
        mind = fminf(mind, v);
      }
    }
  }
  #pragma unroll
  for (int off = 32; off >= 1; off >>= 1) mind = fminf(mind, __shfl_xor(mind, off));
  if (lane == 0) atomicMin(&dmin[b], __float_as_int(fmaxf(mind, 0.f)));
}

// Exact fallback for the 6 negative exp-factors. One block per batch; each
// iteration proven negligible (bound: B*N^2*dmax*e^{ef*dmin}/EPS < 1e-3 when
// ef*(dmin-8) < -55) is skipped; otherwise computed exactly (slow, dead path).
__global__ __launch_bounds__(256) void fb_all(
    const unsigned short* __restrict__ pabf, const unsigned short* __restrict__ pbbf,
    const float* __restrict__ pn, const float* __restrict__ ln,
    float* __restrict__ cost, float* __restrict__ currency,
    const int* __restrict__ dmin, float* __restrict__ out)
{
  const float EF[6] = {-256.f, -64.f, -16.f, -4.f, -1.f, -0.25f};
  int b = blockIdx.x, tid = threadIdx.x;
  float dm = __int_as_float(dmin[b]);
  __shared__ float red[256];
  __shared__ float alpha_l[N_];
  __shared__ float prow[D_];
  const unsigned short* A  = pabf + (size_t)b * N_ * D_;
  const unsigned short* Bm = pbbf + (size_t)b * N_ * D_;
  const float* pnb = pn + (size_t)b * N_;
  const float* lnb = ln + (size_t)b * N_;
  float* costb = cost + (size_t)b * N_;
  float* curb  = currency + (size_t)b * N_;
  for (int it = 0; it < 6; it++){
    float ef = EF[it];
    if (ef * (dm - 8.f) < -55.f) continue;   // provably negligible contribution
    // ---- exact slow path (not expected to execute for this input) ----
    float cost_c[8], colsum_c[8], bw_c[8], costnew_c[8];
    #pragma unroll
    for (int j = 0; j < 8; j++){ cost_c[j] = costb[j*256+tid]; colsum_c[j] = 0.f; }
    for (int r = 0; r < N_; r++){
      prow[tid] = bf2f(A[(size_t)r * D_ + tid]);
      __syncthreads();
      float s_c[8], rs = 0.f;
      for (int j = 0; j < 8; j++){
        int m = j*256+tid; float dot = 0.f;
        for (int k = 0; k < D_; k++) dot += prow[k] * bf2f(Bm[(size_t)m * D_ + k]);
        float d = pnb[r] + lnb[m] - 2.f*dot;
        float s = __expf(ef * d) * cost_c[j];
        s_c[j] = s; rs += s;
      }
      float tot = blockReduceSum(rs, red);
      float a = curb[r] / (tot + EPS_);
      if (tid == 0) alpha_l[r] = a;
      #pragma unroll
      for (int j = 0; j < 8; j++) colsum_c[j] += s_c[j] * a;
      __syncthreads();
    }
    #pragma unroll
    for (int j = 0; j < 8; j++){
      float cs = colsum_c[j];
      float bw = fminf(cost_c[j] / (cs + EPS_), 1.f);
      bw_c[j] = bw; costnew_c[j] = fmaxf(cost_c[j] - bw*cs, 0.f);
    }
    float contrib = 0.f;
    for (int r = 0; r < N_; r++){
      prow[tid] = bf2f(A[(size_t)r * D_ + tid]);
      __syncthreads();
      float a = alpha_l[r], rbs = 0.f;
      for (int j = 0; j < 8; j++){
        int m = j*256+tid; float dot = 0.f;
        for (int k = 0; k < D_; k++) dot += prow[k] * bf2f(Bm[(size_t)m * D_ + k]);
        float d = pnb[r] + lnb[m] - 2.f*dot;
        float bid = __expf(ef * d) * cost_c[j] * a * bw_c[j];
        rbs += bid; contrib += bid * d;
      }
      float tot = blockReduceSum(rbs, red);
      if (tid == 0) curb[r] = fmaxf(curb[r] - tot, 0.f);
      __syncthreads();
    }
    #pragma unroll
    for (int j = 0; j < 8; j++) costb[j*256+tid] = costnew_c[j];
    float ctot = blockReduceSum(contrib, red);
    if (tid == 0) atomicAdd(out, ctot);
    __syncthreads();
  }
}

// ef = 0 closed form: bids = alpha_r * cost_m * bw_m (exp(0*d)=1 exactly), so
// sum(bids*d) = Spn*Sv + Sa*Sln - 2*(sum alpha*p).(sum v*l). O(B*N*D) total.
__global__ __launch_bounds__(256) void cf_scalars(
    const float* __restrict__ cost, const float* __restrict__ currency,
    const float* __restrict__ pn, const float* __restrict__ ln,
    float* __restrict__ alpha, float* __restrict__ v, float* __restrict__ scal)
{
  int b = blockIdx.x, tid = threadIdx.x;
  __shared__ float red[256];
  const float* cb  = cost + (size_t)b * N_;
  const float* ub  = currency + (size_t)b * N_;
  const float* pnb = pn + (size_t)b * N_;
  const float* lnb = ln + (size_t)b * N_;
  float* ab = alpha + (size_t)b * N_;
  float* vb = v + (size_t)b * N_;
  float s = 0.f;
  #pragma unroll
  for (int j = 0; j < 8; j++) s += cb[j*256+tid];
  float Sc = blockReduceSum(s, red);
  float sa = 0.f, spn = 0.f;
  #pragma unroll
  for (int j = 0; j < 8; j++){
    int i = j*256+tid;
    float a = ub[i] / (Sc + EPS_);
    ab[i] = a; sa += a; spn += a * pnb[i];
  }
  float Sa  = blockReduceSum(sa, red);
  float Spn = blockReduceSum(spn, red);
  float sv = 0.f, sln = 0.f;
  #pragma unroll
  for (int j = 0; j < 8; j++){
    int i = j*256+tid;
    float c = cb[i];
    float bw = fminf(c / (c * Sa + EPS_), 1.f);
    float vv = c * bw;
    vb[i] = vv; sv += vv; sln += vv * lnb[i];
  }
  float Sv  = blockReduceSum(sv, red);
  float Sln = blockReduceSum(sln, red);
  if (tid == 0){
    scal[b*4+0] = Sa; scal[b*4+1] = Sv; scal[b*4+2] = Spn; scal[b*4+3] = Sln;
  }
}

// P_b = sum_r alpha_r * preds[b][r][:], L_b = sum_m v_m * labels[b][m][:]  (fp32)
__global__ __launch_bounds__(256) void cf_wsum(
    const float* __restrict__ preds, const float* __restrict__ labels,
    const float* __restrict__ alpha, const float* __restrict__ v,
    float* __restrict__ PL)
{
  int chunk = blockIdx.x, src = blockIdx.y, b = blockIdx.z, tid = threadIdx.x;
  const float* X = (src ? labels : preds) + (size_t)b * N_ * D_ + (size_t)chunk * 64 * D_;
  const float* w = (src ? v : alpha) + (size_t)b * N_ + chunk * 64;
  __shared__ float wl[64];
  if (tid < 64) wl[tid] = w[tid];
  __syncthreads();
  float acc = 0.f;
  #pragma unroll 8
  for (int r = 0; r < 64; r++) acc = fmaf(wl[r], X[(size_t)r * D_ + tid], acc);
  atomicAdd(&PL[((size_t)src * B_ + b) * D_ + tid], acc);
}

__global__ __launch_bounds__(256) void cf_final(
    const float* __restrict__ PL, const float* __restrict__ scal,
    float* __restrict__ out)
{
  int b = blockIdx.x, tid = threadIdx.x;
  __shared__ float red[256];
  float p = PL[(size_t)b * D_ + tid] * PL[((size_t)B_ + b) * D_ + tid];
  float dot = blockReduceSum(p, red);
  if (tid == 0){
    float Sa = scal[b*4+0], Sv = scal[b*4+1], Spn = scal[b*4+2], Sln = scal[b*4+3];
    atomicAdd(out, Spn * Sv + Sa * Sln - 2.f * dot);
  }
}

extern "C" void kernel_launch(void* const* d_in, const int* in_sizes, int n_in,
                              void* d_out, int out_size, void* d_ws, size_t ws_size,
                              hipStream_t stream)
{
  const float* preds  = (const float*)d_in[0];
  const float* labels = (const float*)d_in[1];
  float* out = (float*)d_out;
  char* ws = (char*)d_ws;
  const size_t BN = (size_t)B_ * N_;
  size_t off = 0;
  float* cost     = (float*)(ws + off); off += BN * 4;
  float* currency = (float*)(ws + off); off += BN * 4;
  float* alpha    = (float*)(ws + off); off += BN * 4;
  float* v        = (float*)(ws + off); off += BN * 4;
  float* pn       = (float*)(ws + off); off += BN * 4;
  float* ln       = (float*)(ws + off); off += BN * 4;
  int*   dmin     = (int*)(ws + off);   off += 256;
  float* scal     = (float*)(ws + off); off += 256;
  float* PL       = (float*)(ws + off); off += (size_t)2 * B_ * D_ * 4;
  unsigned short* pabf = (unsigned short*)(ws + off); off += BN * D_ * 2;
  unsigned short* pbbf = (unsigned short*)(ws + off); off += BN * D_ * 2;

  hipMemsetAsync(d_out, 0, sizeof(float), stream);
  init_state<<<dim3(128), 256, 0, stream>>>(cost, currency, dmin, PL, scal);
  prep_kernel<<<dim3((unsigned)(BN / 4)), 256, 0, stream>>>(preds, pabf, pn);
  prep_kernel<<<dim3((unsigned)(BN / 4)), 256, 0, stream>>>(labels, pbbf, ln);
  gemm_minmax<<<dim3(16, 16, B_), 256, 0, stream>>>(pabf, pbbf, pn, ln, dmin);
  fb_all<<<dim3(B_), 256, 0, stream>>>(pabf, pbbf, pn, ln, cost, currency, dmin, out);
  cf_scalars<<<dim3(B_), 256, 0, stream>>>(cost, currency, pn, ln, alpha, v, scal);
  cf_wsum<<<dim3(32, 2, B_), 256, 0, stream>>>(preds, labels, alpha, v, PL);
  cf_final<<<dim3(B_), 256, 0, stream>>>(PL, scal, out);
}

// Round 3
// 317.401 us; speedup vs baseline: 1.9094x; 1.0107x over previous
//
#include <hip/hip_runtime.h>
#include <cstdint>

#define B_ 16
#define N_ 2048
#define D_ 256
#define EPS_ 1e-9f

#define AS1 __attribute__((address_space(1)))
#define AS3 __attribute__((address_space(3)))

typedef float f4 __attribute__((ext_vector_type(4)));
typedef __attribute__((ext_vector_type(8))) short short8;

__device__ inline unsigned short f2bf(float x){
  unsigned int u = __float_as_uint(x);
  u = (u + 0x7fffu + ((u >> 16) & 1u)) >> 16;
  return (unsigned short)u;
}
__device__ inline float bf2f(unsigned short u){
  return __uint_as_float(((unsigned int)u) << 16);
}

__device__ float blockReduceSum(float x, float* red){
  int tid = threadIdx.x;
  red[tid] = x; __syncthreads();
  #pragma unroll
  for (int off = 128; off > 0; off >>= 1){
    if (tid < off) red[tid] += red[tid + off];
    __syncthreads();
  }
  float r = red[0]; __syncthreads();
  return r;
}

// one wave per row of 256: fp32 norm + bf16 conversion; grid.y = src select
__global__ __launch_bounds__(256) void prep_kernel(
    const float* __restrict__ preds, const float* __restrict__ labels,
    unsigned short* __restrict__ pabf, unsigned short* __restrict__ pbbf,
    float* __restrict__ pn, float* __restrict__ ln){
  int s = blockIdx.y;
  const float* src = s ? labels : preds;
  unsigned short* dst = s ? pbbf : pabf;
  float* norms = s ? ln : pn;
  int gw = (blockIdx.x * blockDim.x + threadIdx.x) >> 6;
  int lane = threadIdx.x & 63;
  const float4 v = ((const float4*)(src + (size_t)gw * D_))[lane];
  float sum = v.x*v.x + v.y*v.y + v.z*v.z + v.w*v.w;
  #pragma unroll
  for (int off = 32; off >= 1; off >>= 1) sum += __shfl_xor(sum, off);
  if (lane == 0) norms[gw] = sum;
  ushort4 o; o.x = f2bf(v.x); o.y = f2bf(v.y); o.z = f2bf(v.z); o.w = f2bf(v.w);
  ((ushort4*)(dst + (size_t)gw * D_))[lane] = o;
}

__global__ __launch_bounds__(256) void init_state(float* __restrict__ cost,
    float* __restrict__ currency, int* __restrict__ dmin,
    float* __restrict__ PL, float* __restrict__ scal){
  int i = blockIdx.x * 256 + threadIdx.x;
  if (i < B_ * N_){ cost[i] = 1.f; currency[i] = 1.f; }
  if (i < 2 * B_ * D_) PL[i] = 0.f;
  if (i < B_ * 4) scal[i] = 0.f;
  if (i < B_) dmin[i] = 0x7f7fffff;  // FLT_MAX bits
}

// d[b][n][m] = pn[n] + ln[m] - 2*dot via bf16 MFMA; NO stores — only per-batch min.
// Staging via global_load_lds width=16; XOR swizzle applied on GLOBAL addresses
// (LDS dest must be wave-uniform base + lane*16), LDS content identical to the
// VGPR-staged version.
__global__ __launch_bounds__(256) void gemm_minmax(
    const unsigned short* __restrict__ pa, const unsigned short* __restrict__ pbm,
    const float* __restrict__ pn, const float* __restrict__ ln,
    int* __restrict__ dmin)
{
  int b = blockIdx.z;
  const unsigned short* A  = pa  + (size_t)b * N_ * D_;
  const unsigned short* Bm = pbm + (size_t)b * N_ * D_;
  int tm = blockIdx.x * 128, tn = blockIdx.y * 128;
  __shared__ __align__(16) unsigned short As[128 * 64];
  __shared__ __align__(16) unsigned short Bs[128 * 64];
  int tid = threadIdx.x, lane = tid & 63, w = tid >> 6;
  int wm = (w >> 1) * 64, wn = (w & 1) * 64;
  int quad = lane >> 4, l15 = lane & 15;
  f4 acc[4][4];
  #pragma unroll
  for (int i = 0; i < 4; i++)
    #pragma unroll
    for (int j = 0; j < 4; j++) acc[i][j] = (f4)0.f;
  int lr = lane >> 3, ch = lane & 7;
  int gch = (ch ^ lr) * 8;           // XOR swizzle on the global side (r&7 == lr)
  for (int kt = 0; kt < D_; kt += 64){
    #pragma unroll
    for (int p = 0; p < 4; p++){
      int R = p * 32 + w * 8;
      int r = R + lr;
      __builtin_amdgcn_global_load_lds(
          (const AS1 unsigned int*)(const void*)&A[(size_t)(tm + r) * D_ + kt + gch],
          (AS3 unsigned int*)(void*)&As[R * 64], 16, 0, 0);
      __builtin_amdgcn_global_load_lds(
          (const AS1 unsigned int*)(const void*)&Bm[(size_t)(tn + r) * D_ + kt + gch],
          (AS3 unsigned int*)(void*)&Bs[R * 64], 16, 0, 0);
    }
    __syncthreads();
    #pragma unroll
    for (int ks = 0; ks < 2; ks++){
      short8 af[4], bf[4];
      int j = ks * 4 + quad;
      #pragma unroll
      for (int i = 0; i < 4; i++){
        int ra = wm + i * 16 + l15;
        af[i] = *(const short8*)(&As[ra * 64 + ((j ^ (ra & 7)) * 8)]);
        int rb = wn + i * 16 + l15;
        bf[i] = *(const short8*)(&Bs[rb * 64 + ((j ^ (rb & 7)) * 8)]);
      }
      #pragma unroll
      for (int i = 0; i < 4; i++)
        #pragma unroll
        for (int jj = 0; jj < 4; jj++)
          acc[i][jj] = __builtin_amdgcn_mfma_f32_16x16x32_bf16(af[i], bf[jj], acc[i][jj], 0, 0, 0);
    }
    __syncthreads();
  }
  // epilogue: C/D layout col = lane&15, row = quad*4 + reg — min only, no stores
  float mind = 3.4e38f;
  #pragma unroll
  for (int i = 0; i < 4; i++){
    int grb = tm + wm + i * 16 + quad * 4;
    #pragma unroll
    for (int jj = 0; jj < 4; jj++){
      int gc = tn + wn + jj * 16 + l15;
      float lnv = ln[(size_t)b * N_ + gc];
      #pragma unroll
      for (int reg = 0; reg < 4; reg++){
        float v = pn[(size_t)b * N_ + grb + reg] + lnv - 2.f * acc[i][jj][reg];
        mind = fminf(mind, v);
      }
    }
  }
  #pragma unroll
  for (int off = 32; off >= 1; off >>= 1) mind = fminf(mind, __shfl_xor(mind, off));
  if (lane == 0) atomicMin(&dmin[b], __float_as_int(fmaxf(mind, 0.f)));
}

// Exact fallback for the 6 negative exp-factors. Each iteration proven
// negligible (bound: B*N^2*dmax*e^{ef*dmin}/EPS < 1e-3 when ef*(dmin-8) < -55)
// is skipped; otherwise computed exactly (slow, dead path for this input).
__global__ __launch_bounds__(256) void fb_all(
    const unsigned short* __restrict__ pabf, const unsigned short* __restrict__ pbbf,
    const float* __restrict__ pn, const float* __restrict__ ln,
    float* __restrict__ cost, float* __restrict__ currency,
    const int* __restrict__ dmin, float* __restrict__ out)
{
  const float EF[6] = {-256.f, -64.f, -16.f, -4.f, -1.f, -0.25f};
  int b = blockIdx.x, tid = threadIdx.x;
  float dm = __int_as_float(dmin[b]);
  __shared__ float red[256];
  __shared__ float alpha_l[N_];
  __shared__ float prow[D_];
  const unsigned short* A  = pabf + (size_t)b * N_ * D_;
  const unsigned short* Bm = pbbf + (size_t)b * N_ * D_;
  const float* pnb = pn + (size_t)b * N_;
  const float* lnb = ln + (size_t)b * N_;
  float* costb = cost + (size_t)b * N_;
  float* curb  = currency + (size_t)b * N_;
  for (int it = 0; it < 6; it++){
    float ef = EF[it];
    if (ef * (dm - 8.f) < -55.f) continue;   // provably negligible contribution
    // ---- exact slow path (not expected to execute for this input) ----
    float cost_c[8], colsum_c[8], bw_c[8], costnew_c[8];
    #pragma unroll
    for (int j = 0; j < 8; j++){ cost_c[j] = costb[j*256+tid]; colsum_c[j] = 0.f; }
    for (int r = 0; r < N_; r++){
      prow[tid] = bf2f(A[(size_t)r * D_ + tid]);
      __syncthreads();
      float s_c[8], rs = 0.f;
      for (int j = 0; j < 8; j++){
        int m = j*256+tid; float dot = 0.f;
        for (int k = 0; k < D_; k++) dot += prow[k] * bf2f(Bm[(size_t)m * D_ + k]);
        float d = pnb[r] + lnb[m] - 2.f*dot;
        float s = __expf(ef * d) * cost_c[j];
        s_c[j] = s; rs += s;
      }
      float tot = blockReduceSum(rs, red);
      float a = curb[r] / (tot + EPS_);
      if (tid == 0) alpha_l[r] = a;
      #pragma unroll
      for (int j = 0; j < 8; j++) colsum_c[j] += s_c[j] * a;
      __syncthreads();
    }
    #pragma unroll
    for (int j = 0; j < 8; j++){
      float cs = colsum_c[j];
      float bw = fminf(cost_c[j] / (cs + EPS_), 1.f);
      bw_c[j] = bw; costnew_c[j] = fmaxf(cost_c[j] - bw*cs, 0.f);
    }
    float contrib = 0.f;
    for (int r = 0; r < N_; r++){
      prow[tid] = bf2f(A[(size_t)r * D_ + tid]);
      __syncthreads();
      float a = alpha_l[r], rbs = 0.f;
      for (int j = 0; j < 8; j++){
        int m = j*256+tid; float dot = 0.f;
        for (int k = 0; k < D_; k++) dot += prow[k] * bf2f(Bm[(size_t)m * D_ + k]);
        float d = pnb[r] + lnb[m] - 2.f*dot;
        float bid = __expf(ef * d) * cost_c[j] * a * bw_c[j];
        rbs += bid; contrib += bid * d;
      }
      float tot = blockReduceSum(rbs, red);
      if (tid == 0) curb[r] = fmaxf(curb[r] - tot, 0.f);
      __syncthreads();
    }
    #pragma unroll
    for (int j = 0; j < 8; j++) costb[j*256+tid] = costnew_c[j];
    float ctot = blockReduceSum(contrib, red);
    if (tid == 0) atomicAdd(out, ctot);
    __syncthreads();
  }
}

// ef = 0 closed form: bids = alpha_r * cost_m * bw_m (exp(0*d)=1 exactly), so
// sum(bids*d) = Spn*Sv + Sa*Sln - 2*(sum alpha*p).(sum v*l). O(B*N*D) total.
__global__ __launch_bounds__(256) void cf_scalars(
    const float* __restrict__ cost, const float* __restrict__ currency,
    const float* __restrict__ pn, const float* __restrict__ ln,
    float* __restrict__ alpha, float* __restrict__ v, float* __restrict__ scal)
{
  int b = blockIdx.x, tid = threadIdx.x;
  __shared__ float red[256];
  const float* cb  = cost + (size_t)b * N_;
  const float* ub  = currency + (size_t)b * N_;
  const float* pnb = pn + (size_t)b * N_;
  const float* lnb = ln + (size_t)b * N_;
  float* ab = alpha + (size_t)b * N_;
  float* vb = v + (size_t)b * N_;
  float s = 0.f;
  #pragma unroll
  for (int j = 0; j < 8; j++) s += cb[j*256+tid];
  float Sc = blockReduceSum(s, red);
  float sa = 0.f, spn = 0.f;
  #pragma unroll
  for (int j = 0; j < 8; j++){
    int i = j*256+tid;
    float a = ub[i] / (Sc + EPS_);
    ab[i] = a; sa += a; spn += a * pnb[i];
  }
  float Sa  = blockReduceSum(sa, red);
  float Spn = blockReduceSum(spn, red);
  float sv = 0.f, sln = 0.f;
  #pragma unroll
  for (int j = 0; j < 8; j++){
    int i = j*256+tid;
    float c = cb[i];
    float bw = fminf(c / (c * Sa + EPS_), 1.f);
    float vv = c * bw;
    vb[i] = vv; sv += vv; sln += vv * lnb[i];
  }
  float Sv  = blockReduceSum(sv, red);
  float Sln = blockReduceSum(sln, red);
  if (tid == 0){
    scal[b*4+0] = Sa; scal[b*4+1] = Sv; scal[b*4+2] = Spn; scal[b*4+3] = Sln;
  }
}

// P_b = sum_r alpha_r * preds[b][r][:], L_b = sum_m v_m * labels[b][m][:]
// bf16 sources (error enters only the tiny -2*P.L term), uint2 loads,
// LDS-combine across the 4 row-groups, one atomicAdd per col.
__global__ __launch_bounds__(256) void cf_wsum(
    const unsigned short* __restrict__ pabf, const unsigned short* __restrict__ pbbf,
    const float* __restrict__ alpha, const float* __restrict__ v,
    float* __restrict__ PL)
{
  int chunk = blockIdx.x, src = blockIdx.y, b = blockIdx.z, tid = threadIdx.x;
  int g = tid >> 6, c4 = (tid & 63) * 4;
  const unsigned short* X = (src ? pbbf : pabf) + ((size_t)b * N_ + chunk * 64) * D_;
  const float* wv = (src ? v : alpha) + (size_t)b * N_ + chunk * 64;
  __shared__ float wl[64];
  __shared__ float part[4][D_];
  if (tid < 64) wl[tid] = wv[tid];
  __syncthreads();
  f4 acc = (f4)0.f;
  for (int r = g * 16; r < g * 16 + 16; r++){
    uint2 pk = *(const uint2*)&X[(size_t)r * D_ + c4];
    float wr = wl[r];
    acc[0] = fmaf(wr, __uint_as_float(pk.x << 16), acc[0]);
    acc[1] = fmaf(wr, __uint_as_float(pk.x & 0xffff0000u), acc[1]);
    acc[2] = fmaf(wr, __uint_as_float(pk.y << 16), acc[2]);
    acc[3] = fmaf(wr, __uint_as_float(pk.y & 0xffff0000u), acc[3]);
  }
  #pragma unroll
  for (int q = 0; q < 4; q++) part[g][c4 + q] = acc[q];
  __syncthreads();
  float s = part[0][tid] + part[1][tid] + part[2][tid] + part[3][tid];
  atomicAdd(&PL[((size_t)src * B_ + b) * D_ + tid], s);
}

__global__ __launch_bounds__(256) void cf_final(
    const float* __restrict__ PL, const float* __restrict__ scal,
    float* __restrict__ out)
{
  int b = blockIdx.x, tid = threadIdx.x;
  __shared__ float red[256];
  float p = PL[(size_t)b * D_ + tid] * PL[((size_t)B_ + b) * D_ + tid];
  float dot = blockReduceSum(p, red);
  if (tid == 0){
    float Sa = scal[b*4+0], Sv = scal[b*4+1], Spn = scal[b*4+2], Sln = scal[b*4+3];
    atomicAdd(out, Spn * Sv + Sa * Sln - 2.f * dot);
  }
}

extern "C" void kernel_launch(void* const* d_in, const int* in_sizes, int n_in,
                              void* d_out, int out_size, void* d_ws, size_t ws_size,
                              hipStream_t stream)
{
  const float* preds  = (const float*)d_in[0];
  const float* labels = (const float*)d_in[1];
  float* out = (float*)d_out;
  char* ws = (char*)d_ws;
  const size_t BN = (size_t)B_ * N_;
  size_t off = 0;
  float* cost     = (float*)(ws + off); off += BN * 4;
  float* currency = (float*)(ws + off); off += BN * 4;
  float* alpha    = (float*)(ws + off); off += BN * 4;
  float* v        = (float*)(ws + off); off += BN * 4;
  float* pn       = (float*)(ws + off); off += BN * 4;
  float* ln       = (float*)(ws + off); off += BN * 4;
  int*   dmin     = (int*)(ws + off);   off += 256;
  float* scal     = (float*)(ws + off); off += 256;
  float* PL       = (float*)(ws + off); off += (size_t)2 * B_ * D_ * 4;
  unsigned short* pabf = (unsigned short*)(ws + off); off += BN * D_ * 2;
  unsigned short* pbbf = (unsigned short*)(ws + off); off += BN * D_ * 2;

  hipMemsetAsync(d_out, 0, sizeof(float), stream);
  init_state<<<dim3(128), 256, 0, stream>>>(cost, currency, dmin, PL, scal);
  prep_kernel<<<dim3((unsigned)(BN / 4), 2), 256, 0, stream>>>(preds, labels, pabf, pbbf, pn, ln);
  gemm_minmax<<<dim3(16, 16, B_), 256, 0, stream>>>(pabf, pbbf, pn, ln, dmin);
  fb_all<<<dim3(B_), 256, 0, stream>>>(pabf, pbbf, pn, ln, cost, currency, dmin, out);
  cf_scalars<<<dim3(B_), 256, 0, stream>>>(cost, currency, pn, ln, alpha, v, scal);
  cf_wsum<<<dim3(32, 2, B_), 256, 0, stream>>>(pabf, pbbf, alpha, v, PL);
  cf_final<<<dim3(B_), 256, 0, stream>>>(PL, scal, out);
}

// Round 4
// 176.005 us; speedup vs baseline: 3.4433x; 1.8034x over previous
//
#include <hip/hip_runtime.h>
#include <cstdint>

#define B_ 16
#define N_ 2048
#define D_ 256
#define EPS_ 1e-9f

#define AS1 __attribute__((address_space(1)))
#define AS3 __attribute__((address_space(3)))

typedef float f4 __attribute__((ext_vector_type(4)));
typedef __attribute__((ext_vector_type(8))) short short8;

__device__ inline unsigned short f2bf(float x){
  unsigned int u = __float_as_uint(x);
  u = (u + 0x7fffu + ((u >> 16) & 1u)) >> 16;
  return (unsigned short)u;
}
__device__ inline float bf2f(unsigned short u){
  return __uint_as_float(((unsigned int)u) << 16);
}

__device__ float blockReduceSum(float x, float* red){
  int tid = threadIdx.x;
  red[tid] = x; __syncthreads();
  #pragma unroll
  for (int off = 128; off > 0; off >>= 1){
    if (tid < off) red[tid] += red[tid + off];
    __syncthreads();
  }
  float r = red[0]; __syncthreads();
  return r;
}

// one wave per row of 256: fp32 norm + bf16 conversion; grid.y = src select
__global__ __launch_bounds__(256) void prep_kernel(
    const float* __restrict__ preds, const float* __restrict__ labels,
    unsigned short* __restrict__ pabf, unsigned short* __restrict__ pbbf,
    float* __restrict__ pn, float* __restrict__ ln){
  int s = blockIdx.y;
  const float* src = s ? labels : preds;
  unsigned short* dst = s ? pbbf : pabf;
  float* norms = s ? ln : pn;
  int gw = (blockIdx.x * blockDim.x + threadIdx.x) >> 6;
  int lane = threadIdx.x & 63;
  const float4 v = ((const float4*)(src + (size_t)gw * D_))[lane];
  float sum = v.x*v.x + v.y*v.y + v.z*v.z + v.w*v.w;
  #pragma unroll
  for (int off = 32; off >= 1; off >>= 1) sum += __shfl_xor(sum, off);
  if (lane == 0) norms[gw] = sum;
  ushort4 o; o.x = f2bf(v.x); o.y = f2bf(v.y); o.z = f2bf(v.z); o.w = f2bf(v.w);
  ((ushort4*)(dst + (size_t)gw * D_))[lane] = o;
}

__global__ __launch_bounds__(256) void init_state(float* __restrict__ cost,
    float* __restrict__ currency, int* __restrict__ dmin,
    float* __restrict__ PL, float* __restrict__ scal){
  int i = blockIdx.x * 256 + threadIdx.x;
  if (i < B_ * N_){ cost[i] = 1.f; currency[i] = 1.f; }
  if (i < 2 * B_ * D_) PL[i] = 0.f;
  if (i < B_ * 4) scal[i] = 0.f;
  if (i < B_) dmin[i] = 0x7f7fffff;  // FLT_MAX bits
}

// d[b][n][m] = pn[n] + ln[m] - 2*dot via bf16 MFMA; NO stores — only per-batch min.
// Double-buffered LDS (prefetch k+1 before computing k) + pn/ln preloaded into
// registers before the K-loop so the epilogue is pure register math.
__global__ __launch_bounds__(256) void gemm_minmax(
    const unsigned short* __restrict__ pa, const unsigned short* __restrict__ pbm,
    const float* __restrict__ pn, const float* __restrict__ ln,
    int* __restrict__ dmin)
{
  int b = blockIdx.z;
  const unsigned short* A  = pa  + (size_t)b * N_ * D_;
  const unsigned short* Bm = pbm + (size_t)b * N_ * D_;
  int tm = blockIdx.x * 128, tn = blockIdx.y * 128;
  __shared__ __align__(16) unsigned short As[2][128 * 64];
  __shared__ __align__(16) unsigned short Bs[2][128 * 64];
  __shared__ float minred[4];
  int tid = threadIdx.x, lane = tid & 63, w = tid >> 6;
  int wm = (w >> 1) * 64, wn = (w & 1) * 64;
  int quad = lane >> 4, l15 = lane & 15;

  // ---- preload epilogue operands (K-independent) into registers ----
  float4 pnr[4];
  float lnr[4];
  #pragma unroll
  for (int i = 0; i < 4; i++)
    pnr[i] = *(const float4*)&pn[(size_t)b * N_ + tm + wm + i * 16 + quad * 4];
  #pragma unroll
  for (int jj = 0; jj < 4; jj++)
    lnr[jj] = ln[(size_t)b * N_ + tn + wn + jj * 16 + l15];

  f4 acc[4][4];
  #pragma unroll
  for (int i = 0; i < 4; i++)
    #pragma unroll
    for (int j = 0; j < 4; j++) acc[i][j] = (f4)0.f;

  int lr = lane >> 3, ch = lane & 7;
  int gch = (ch ^ lr) * 8;           // XOR swizzle on the GLOBAL side (r&7 == lr)

  // prefetch tile 0 into buffer 0
  #pragma unroll
  for (int p = 0; p < 4; p++){
    int R = p * 32 + w * 8;
    int r = R + lr;
    __builtin_amdgcn_global_load_lds(
        (const AS1 unsigned int*)(const void*)&A[(size_t)(tm + r) * D_ + gch],
        (AS3 unsigned int*)(void*)&As[0][R * 64], 16, 0, 0);
    __builtin_amdgcn_global_load_lds(
        (const AS1 unsigned int*)(const void*)&Bm[(size_t)(tn + r) * D_ + gch],
        (AS3 unsigned int*)(void*)&Bs[0][R * 64], 16, 0, 0);
  }

  int buf = 0;
  for (int ki = 0; ki < 4; ki++){
    __syncthreads();   // drains buf's loads (issued one compute-phase ago)
    if (ki < 3){
      int kt = (ki + 1) * 64;
      #pragma unroll
      for (int p = 0; p < 4; p++){
        int R = p * 32 + w * 8;
        int r = R + lr;
        __builtin_amdgcn_global_load_lds(
            (const AS1 unsigned int*)(const void*)&A[(size_t)(tm + r) * D_ + kt + gch],
            (AS3 unsigned int*)(void*)&As[buf ^ 1][R * 64], 16, 0, 0);
        __builtin_amdgcn_global_load_lds(
            (const AS1 unsigned int*)(const void*)&Bm[(size_t)(tn + r) * D_ + kt + gch],
            (AS3 unsigned int*)(void*)&Bs[buf ^ 1][R * 64], 16, 0, 0);
      }
    }
    #pragma unroll
    for (int ks = 0; ks < 2; ks++){
      short8 af[4], bf[4];
      int j = ks * 4 + quad;
      #pragma unroll
      for (int i = 0; i < 4; i++){
        int ra = wm + i * 16 + l15;
        af[i] = *(const short8*)(&As[buf][ra * 64 + ((j ^ (ra & 7)) * 8)]);
        int rb = wn + i * 16 + l15;
        bf[i] = *(const short8*)(&Bs[buf][rb * 64 + ((j ^ (rb & 7)) * 8)]);
      }
      #pragma unroll
      for (int i = 0; i < 4; i++)
        #pragma unroll
        for (int jj = 0; jj < 4; jj++)
          acc[i][jj] = __builtin_amdgcn_mfma_f32_16x16x32_bf16(af[i], bf[jj], acc[i][jj], 0, 0, 0);
    }
    buf ^= 1;
  }

  // epilogue: C/D layout col = lane&15, row = quad*4 + reg — registers only
  float mind = 3.4e38f;
  #pragma unroll
  for (int i = 0; i < 4; i++){
    float pv[4] = {pnr[i].x, pnr[i].y, pnr[i].z, pnr[i].w};
    #pragma unroll
    for (int jj = 0; jj < 4; jj++){
      #pragma unroll
      for (int reg = 0; reg < 4; reg++){
        float v = pv[reg] + lnr[jj] - 2.f * acc[i][jj][reg];
        mind = fminf(mind, v);
      }
    }
  }
  #pragma unroll
  for (int off = 32; off >= 1; off >>= 1) mind = fminf(mind, __shfl_xor(mind, off));
  if (lane == 0) minred[w] = mind;
  __syncthreads();
  if (tid == 0){
    float m = fminf(fminf(minred[0], minred[1]), fminf(minred[2], minred[3]));
    atomicMin(&dmin[b], __float_as_int(fmaxf(m, 0.f)));
  }
}

// Exact fallback for the 6 negative exp-factors. Each iteration proven
// negligible (bound: B*N^2*dmax*e^{ef*dmin}/EPS < 1e-3 when ef*(dmin-8) < -55)
// is skipped; otherwise computed exactly (slow, dead path for this input).
__global__ __launch_bounds__(256) void fb_all(
    const unsigned short* __restrict__ pabf, const unsigned short* __restrict__ pbbf,
    const float* __restrict__ pn, const float* __restrict__ ln,
    float* __restrict__ cost, float* __restrict__ currency,
    const int* __restrict__ dmin, float* __restrict__ out)
{
  const float EF[6] = {-256.f, -64.f, -16.f, -4.f, -1.f, -0.25f};
  int b = blockIdx.x, tid = threadIdx.x;
  float dm = __int_as_float(dmin[b]);
  __shared__ float red[256];
  __shared__ float alpha_l[N_];
  __shared__ float prow[D_];
  const unsigned short* A  = pabf + (size_t)b * N_ * D_;
  const unsigned short* Bm = pbbf + (size_t)b * N_ * D_;
  const float* pnb = pn + (size_t)b * N_;
  const float* lnb = ln + (size_t)b * N_;
  float* costb = cost + (size_t)b * N_;
  float* curb  = currency + (size_t)b * N_;
  for (int it = 0; it < 6; it++){
    float ef = EF[it];
    if (ef * (dm - 8.f) < -55.f) continue;   // provably negligible contribution
    // ---- exact slow path (not expected to execute for this input) ----
    float cost_c[8], colsum_c[8], bw_c[8], costnew_c[8];
    #pragma unroll
    for (int j = 0; j < 8; j++){ cost_c[j] = costb[j*256+tid]; colsum_c[j] = 0.f; }
    for (int r = 0; r < N_; r++){
      prow[tid] = bf2f(A[(size_t)r * D_ + tid]);
      __syncthreads();
      float s_c[8], rs = 0.f;
      for (int j = 0; j < 8; j++){
        int m = j*256+tid; float dot = 0.f;
        for (int k = 0; k < D_; k++) dot += prow[k] * bf2f(Bm[(size_t)m * D_ + k]);
        float d = pnb[r] + lnb[m] - 2.f*dot;
        float s = __expf(ef * d) * cost_c[j];
        s_c[j] = s; rs += s;
      }
      float tot = blockReduceSum(rs, red);
      float a = curb[r] / (tot + EPS_);
      if (tid == 0) alpha_l[r] = a;
      #pragma unroll
      for (int j = 0; j < 8; j++) colsum_c[j] += s_c[j] * a;
      __syncthreads();
    }
    #pragma unroll
    for (int j = 0; j < 8; j++){
      float cs = colsum_c[j];
      float bw = fminf(cost_c[j] / (cs + EPS_), 1.f);
      bw_c[j] = bw; costnew_c[j] = fmaxf(cost_c[j] - bw*cs, 0.f);
    }
    float contrib = 0.f;
    for (int r = 0; r < N_; r++){
      prow[tid] = bf2f(A[(size_t)r * D_ + tid]);
      __syncthreads();
      float a = alpha_l[r], rbs = 0.f;
      for (int j = 0; j < 8; j++){
        int m = j*256+tid; float dot = 0.f;
        for (int k = 0; k < D_; k++) dot += prow[k] * bf2f(Bm[(size_t)m * D_ + k]);
        float d = pnb[r] + lnb[m] - 2.f*dot;
        float bid = __expf(ef * d) * cost_c[j] * a * bw_c[j];
        rbs += bid; contrib += bid * d;
      }
      float tot = blockReduceSum(rbs, red);
      if (tid == 0) curb[r] = fmaxf(curb[r] - tot, 0.f);
      __syncthreads();
    }
    #pragma unroll
    for (int j = 0; j < 8; j++) costb[j*256+tid] = costnew_c[j];
    float ctot = blockReduceSum(contrib, red);
    if (tid == 0) atomicAdd(out, ctot);
    __syncthreads();
  }
}

// ef = 0 closed form: bids = alpha_r * cost_m * bw_m (exp(0*d)=1 exactly), so
// sum(bids*d) = Spn*Sv + Sa*Sln - 2*(sum alpha*p).(sum v*l). O(B*N*D) total.
__global__ __launch_bounds__(256) void cf_scalars(
    const float* __restrict__ cost, const float* __restrict__ currency,
    const float* __restrict__ pn, const float* __restrict__ ln,
    float* __restrict__ alpha, float* __restrict__ v, float* __restrict__ scal)
{
  int b = blockIdx.x, tid = threadIdx.x;
  __shared__ float red[256];
  const float* cb  = cost + (size_t)b * N_;
  const float* ub  = currency + (size_t)b * N_;
  const float* pnb = pn + (size_t)b * N_;
  const float* lnb = ln + (size_t)b * N_;
  float* ab = alpha + (size_t)b * N_;
  float* vb = v + (size_t)b * N_;
  float s = 0.f;
  #pragma unroll
  for (int j = 0; j < 8; j++) s += cb[j*256+tid];
  float Sc = blockReduceSum(s, red);
  float sa = 0.f, spn = 0.f;
  #pragma unroll
  for (int j = 0; j < 8; j++){
    int i = j*256+tid;
    float a = ub[i] / (Sc + EPS_);
    ab[i] = a; sa += a; spn += a * pnb[i];
  }
  float Sa  = blockReduceSum(sa, red);
  float Spn = blockReduceSum(spn, red);
  float sv = 0.f, sln = 0.f;
  #pragma unroll
  for (int j = 0; j < 8; j++){
    int i = j*256+tid;
    float c = cb[i];
    float bw = fminf(c / (c * Sa + EPS_), 1.f);
    float vv = c * bw;
    vb[i] = vv; sv += vv; sln += vv * lnb[i];
  }
  float Sv  = blockReduceSum(sv, red);
  float Sln = blockReduceSum(sln, red);
  if (tid == 0){
    scal[b*4+0] = Sa; scal[b*4+1] = Sv; scal[b*4+2] = Spn; scal[b*4+3] = Sln;
  }
}

// P_b = sum_r alpha_r * preds[b][r][:], L_b = sum_m v_m * labels[b][m][:]
// bf16 sources (error enters only the tiny -2*P.L term), uint2 loads,
// LDS-combine across the 4 row-groups, one atomicAdd per col.
__global__ __launch_bounds__(256) void cf_wsum(
    const unsigned short* __restrict__ pabf, const unsigned short* __restrict__ pbbf,
    const float* __restrict__ alpha, const float* __restrict__ v,
    float* __restrict__ PL)
{
  int chunk = blockIdx.x, src = blockIdx.y, b = blockIdx.z, tid = threadIdx.x;
  int g = tid >> 6, c4 = (tid & 63) * 4;
  const unsigned short* X = (src ? pbbf : pabf) + ((size_t)b * N_ + chunk * 64) * D_;
  const float* wv = (src ? v : alpha) + (size_t)b * N_ + chunk * 64;
  __shared__ float wl[64];
  __shared__ float part[4][D_];
  if (tid < 64) wl[tid] = wv[tid];
  __syncthreads();
  f4 acc = (f4)0.f;
  for (int r = g * 16; r < g * 16 + 16; r++){
    uint2 pk = *(const uint2*)&X[(size_t)r * D_ + c4];
    float wr = wl[r];
    acc[0] = fmaf(wr, __uint_as_float(pk.x << 16), acc[0]);
    acc[1] = fmaf(wr, __uint_as_float(pk.x & 0xffff0000u), acc[1]);
    acc[2] = fmaf(wr, __uint_as_float(pk.y << 16), acc[2]);
    acc[3] = fmaf(wr, __uint_as_float(pk.y & 0xffff0000u), acc[3]);
  }
  #pragma unroll
  for (int q = 0; q < 4; q++) part[g][c4 + q] = acc[q];
  __syncthreads();
  float s = part[0][tid] + part[1][tid] + part[2][tid] + part[3][tid];
  atomicAdd(&PL[((size_t)src * B_ + b) * D_ + tid], s);
}

__global__ __launch_bounds__(256) void cf_final(
    const float* __restrict__ PL, const float* __restrict__ scal,
    float* __restrict__ out)
{
  int b = blockIdx.x, tid = threadIdx.x;
  __shared__ float red[256];
  float p = PL[(size_t)b * D_ + tid] * PL[((size_t)B_ + b) * D_ + tid];
  float dot = blockReduceSum(p, red);
  if (tid == 0){
    float Sa = scal[b*4+0], Sv = scal[b*4+1], Spn = scal[b*4+2], Sln = scal[b*4+3];
    atomicAdd(out, Spn * Sv + Sa * Sln - 2.f * dot);
  }
}

extern "C" void kernel_launch(void* const* d_in, const int* in_sizes, int n_in,
                              void* d_out, int out_size, void* d_ws, size_t ws_size,
                              hipStream_t stream)
{
  const float* preds  = (const float*)d_in[0];
  const float* labels = (const float*)d_in[1];
  float* out = (float*)d_out;
  char* ws = (char*)d_ws;
  const size_t BN = (size_t)B_ * N_;
  size_t off = 0;
  float* cost     = (float*)(ws + off); off += BN * 4;
  float* currency = (float*)(ws + off); off += BN * 4;
  float* alpha    = (float*)(ws + off); off += BN * 4;
  float* v        = (float*)(ws + off); off += BN * 4;
  float* pn       = (float*)(ws + off); off += BN * 4;
  float* ln       = (float*)(ws + off); off += BN * 4;
  int*   dmin     = (int*)(ws + off);   off += 256;
  float* scal     = (float*)(ws + off); off += 256;
  float* PL       = (float*)(ws + off); off += (size_t)2 * B_ * D_ * 4;
  unsigned short* pabf = (unsigned short*)(ws + off); off += BN * D_ * 2;
  unsigned short* pbbf = (unsigned short*)(ws + off); off += BN * D_ * 2;

  hipMemsetAsync(d_out, 0, sizeof(float), stream);
  init_state<<<dim3(128), 256, 0, stream>>>(cost, currency, dmin, PL, scal);
  prep_kernel<<<dim3((unsigned)(BN / 4), 2), 256, 0, stream>>>(preds, labels, pabf, pbbf, pn, ln);
  gemm_minmax<<<dim3(16, 16, B_), 256, 0, stream>>>(pabf, pbbf, pn, ln, dmin);
  fb_all<<<dim3(B_), 256, 0, stream>>>(pabf, pbbf, pn, ln, cost, currency, dmin, out);
  cf_scalars<<<dim3(B_), 256, 0, stream>>>(cost, currency, pn, ln, alpha, v, scal);
  cf_wsum<<<dim3(32, 2, B_), 256, 0, stream>>>(pabf, pbbf, alpha, v, PL);
  cf_final<<<dim3(B_), 256, 0, stream>>>(PL, scal, out);
}

// Round 5
// 163.372 us; speedup vs baseline: 3.7095x; 1.0773x over previous
//
#include <hip/hip_runtime.h>
#include <cstdint>

#define B_ 16
#define N_ 2048
#define D_ 256
#define EPS_ 1e-9f

#define AS1 __attribute__((address_space(1)))
#define AS3 __attribute__((address_space(3)))

typedef float f4 __attribute__((ext_vector_type(4)));
typedef __attribute__((ext_vector_type(8))) short short8;

__device__ inline unsigned short f2bf(float x){
  unsigned int u = __float_as_uint(x);
  u = (u + 0x7fffu + ((u >> 16) & 1u)) >> 16;
  return (unsigned short)u;
}
__device__ inline float bf2f(unsigned short u){
  return __uint_as_float(((unsigned int)u) << 16);
}

__device__ float blockReduceSum(float x, float* red){
  int tid = threadIdx.x;
  red[tid] = x; __syncthreads();
  #pragma unroll
  for (int off = 128; off > 0; off >>= 1){
    if (tid < off) red[tid] += red[tid + off];
    __syncthreads();
  }
  float r = red[0]; __syncthreads();
  return r;
}

// fp32 norm + bf16 conversion; grid.y = src select. Also folds all state init.
__global__ __launch_bounds__(256) void prep_kernel(
    const float* __restrict__ preds, const float* __restrict__ labels,
    unsigned short* __restrict__ pabf, unsigned short* __restrict__ pbbf,
    float* __restrict__ pn, float* __restrict__ ln,
    float* __restrict__ cost, float* __restrict__ currency,
    int* __restrict__ dmin, float* __restrict__ PL,
    float* __restrict__ scal, float* __restrict__ out){
  int s = blockIdx.y;
  if (s == 0){
    int i = blockIdx.x * 256 + threadIdx.x;
    if (i < B_ * N_){ cost[i] = 1.f; currency[i] = 1.f; }
    if (i < 2 * B_ * D_) PL[i] = 0.f;
    if (i < B_ * 4) scal[i] = 0.f;
    if (i < B_) dmin[i] = 0x7f7fffff;  // FLT_MAX bits
    if (i == 0) out[0] = 0.f;
  }
  const float* src = s ? labels : preds;
  unsigned short* dst = s ? pbbf : pabf;
  float* norms = s ? ln : pn;
  int gw = (blockIdx.x * blockDim.x + threadIdx.x) >> 6;
  int lane = threadIdx.x & 63;
  const float4 v = ((const float4*)(src + (size_t)gw * D_))[lane];
  float sum = v.x*v.x + v.y*v.y + v.z*v.z + v.w*v.w;
  #pragma unroll
  for (int off = 32; off >= 1; off >>= 1) sum += __shfl_xor(sum, off);
  if (lane == 0) norms[gw] = sum;
  ushort4 o; o.x = f2bf(v.x); o.y = f2bf(v.y); o.z = f2bf(v.z); o.w = f2bf(v.w);
  ((ushort4*)(dst + (size_t)gw * D_))[lane] = o;
}

// d[b][n][m] = pn[n] + ln[m] - 2*dot via bf16 MFMA; NO stores — only per-batch min.
// Block tile 256x128, BK=32, wave tile 128x64 (LDS bytes/FLOP = 0.75x of 64x64).
// Double-buffered, global_load_lds w=16, XOR swizzle f(r)=(r+(r>>2))&3 on 64-B rows
// (<=2-way bank aliasing on both write and read sides).
__global__ __launch_bounds__(256, 2) void gemm_minmax(
    const unsigned short* __restrict__ pa, const unsigned short* __restrict__ pbm,
    const float* __restrict__ pn, const float* __restrict__ ln,
    int* __restrict__ dmin)
{
  int b = blockIdx.z;
  const unsigned short* A  = pa  + (size_t)b * N_ * D_;
  const unsigned short* Bm = pbm + (size_t)b * N_ * D_;
  int tm = blockIdx.x * 256, tn = blockIdx.y * 128;
  __shared__ __align__(16) unsigned short As[2][256 * 32];
  __shared__ __align__(16) unsigned short Bs[2][128 * 32];
  __shared__ float minred[4];
  int tid = threadIdx.x, lane = tid & 63, w = tid >> 6;
  int wm = (w >> 1) * 128, wn = (w & 1) * 64;
  int quad = lane >> 4, l15 = lane & 15;

  f4 acc[8][4];
  #pragma unroll
  for (int i = 0; i < 8; i++)
    #pragma unroll
    for (int j = 0; j < 4; j++) acc[i][j] = (f4)0.f;

  int lr = lane >> 2, lc = lane & 3;

  // prefetch tile 0 into buffer 0
  #pragma unroll
  for (int p = 0; p < 4; p++){
    int R = w * 64 + p * 16, r = R + lr;
    int c = lc ^ ((r + (r >> 2)) & 3);
    __builtin_amdgcn_global_load_lds(
        (const AS1 unsigned int*)(const void*)&A[(size_t)(tm + r) * D_ + c * 8],
        (AS3 unsigned int*)(void*)&As[0][R * 32], 16, 0, 0);
  }
  #pragma unroll
  for (int p = 0; p < 2; p++){
    int R = w * 32 + p * 16, r = R + lr;
    int c = lc ^ ((r + (r >> 2)) & 3);
    __builtin_amdgcn_global_load_lds(
        (const AS1 unsigned int*)(const void*)&Bm[(size_t)(tn + r) * D_ + c * 8],
        (AS3 unsigned int*)(void*)&Bs[0][R * 32], 16, 0, 0);
  }

  int buf = 0;
  for (int ki = 0; ki < 8; ki++){
    __syncthreads();   // drains buf's loads (issued one compute-phase ago)
    if (ki < 7){
      int kt = (ki + 1) * 32;
      #pragma unroll
      for (int p = 0; p < 4; p++){
        int R = w * 64 + p * 16, r = R + lr;
        int c = lc ^ ((r + (r >> 2)) & 3);
        __builtin_amdgcn_global_load_lds(
            (const AS1 unsigned int*)(const void*)&A[(size_t)(tm + r) * D_ + kt + c * 8],
            (AS3 unsigned int*)(void*)&As[buf ^ 1][R * 32], 16, 0, 0);
      }
      #pragma unroll
      for (int p = 0; p < 2; p++){
        int R = w * 32 + p * 16, r = R + lr;
        int c = lc ^ ((r + (r >> 2)) & 3);
        __builtin_amdgcn_global_load_lds(
            (const AS1 unsigned int*)(const void*)&Bm[(size_t)(tn + r) * D_ + kt + c * 8],
            (AS3 unsigned int*)(void*)&Bs[buf ^ 1][R * 32], 16, 0, 0);
      }
    }
    short8 af[8], bf[4];
    #pragma unroll
    for (int i = 0; i < 8; i++){
      int ra = wm + i * 16 + l15;
      af[i] = *(const short8*)(&As[buf][ra * 32 + ((quad ^ ((ra + (ra >> 2)) & 3)) * 8)]);
    }
    #pragma unroll
    for (int jj = 0; jj < 4; jj++){
      int rb = wn + jj * 16 + l15;
      bf[jj] = *(const short8*)(&Bs[buf][rb * 32 + ((quad ^ ((rb + (rb >> 2)) & 3)) * 8)]);
    }
    #pragma unroll
    for (int i = 0; i < 8; i++)
      #pragma unroll
      for (int jj = 0; jj < 4; jj++)
        acc[i][jj] = __builtin_amdgcn_mfma_f32_16x16x32_bf16(af[i], bf[jj], acc[i][jj], 0, 0, 0);
    buf ^= 1;
  }

  // epilogue: C/D layout col = lane&15, row = quad*4 + reg. Load norms post-loop
  // (keeps K-loop VGPR pressure down), batched issue, then register math.
  float4 pnr[8];
  float lnr[4];
  #pragma unroll
  for (int i = 0; i < 8; i++)
    pnr[i] = *(const float4*)&pn[(size_t)b * N_ + tm + wm + i * 16 + quad * 4];
  #pragma unroll
  for (int jj = 0; jj < 4; jj++)
    lnr[jj] = ln[(size_t)b * N_ + tn + wn + jj * 16 + l15];
  float mind = 3.4e38f;
  #pragma unroll
  for (int i = 0; i < 8; i++){
    float pv[4] = {pnr[i].x, pnr[i].y, pnr[i].z, pnr[i].w};
    #pragma unroll
    for (int jj = 0; jj < 4; jj++){
      #pragma unroll
      for (int reg = 0; reg < 4; reg++){
        float v = pv[reg] + lnr[jj] - 2.f * acc[i][jj][reg];
        mind = fminf(mind, v);
      }
    }
  }
  #pragma unroll
  for (int off = 32; off >= 1; off >>= 1) mind = fminf(mind, __shfl_xor(mind, off));
  if (lane == 0) minred[w] = mind;
  __syncthreads();
  if (tid == 0){
    float m = fminf(fminf(minred[0], minred[1]), fminf(minred[2], minred[3]));
    atomicMin(&dmin[b], __float_as_int(fmaxf(m, 0.f)));
  }
}

// Exact fallback for the 6 negative exp-factors (skipped when provably
// negligible: B*N^2*dmax*e^{ef*dmin}/EPS < 1e-3 iff ef*(dmin-8) < -55),
// followed by the ef=0 closed-form scalars (fused former cf_scalars).
__global__ __launch_bounds__(256) void fb_all(
    const unsigned short* __restrict__ pabf, const unsigned short* __restrict__ pbbf,
    const float* __restrict__ pn, const float* __restrict__ ln,
    float* __restrict__ cost, float* __restrict__ currency,
    const int* __restrict__ dmin, float* __restrict__ out,
    float* __restrict__ alpha, float* __restrict__ v, float* __restrict__ scal)
{
  const float EF[6] = {-256.f, -64.f, -16.f, -4.f, -1.f, -0.25f};
  int b = blockIdx.x, tid = threadIdx.x;
  float dm = __int_as_float(dmin[b]);
  __shared__ float red[256];
  __shared__ float alpha_l[N_];
  __shared__ float prow[D_];
  const unsigned short* A  = pabf + (size_t)b * N_ * D_;
  const unsigned short* Bm = pbbf + (size_t)b * N_ * D_;
  const float* pnb = pn + (size_t)b * N_;
  const float* lnb = ln + (size_t)b * N_;
  float* costb = cost + (size_t)b * N_;
  float* curb  = currency + (size_t)b * N_;
  for (int it = 0; it < 6; it++){
    float ef = EF[it];
    if (ef * (dm - 8.f) < -55.f) continue;   // provably negligible contribution
    // ---- exact slow path (not expected to execute for this input) ----
    float cost_c[8], colsum_c[8], bw_c[8], costnew_c[8];
    #pragma unroll
    for (int j = 0; j < 8; j++){ cost_c[j] = costb[j*256+tid]; colsum_c[j] = 0.f; }
    for (int r = 0; r < N_; r++){
      prow[tid] = bf2f(A[(size_t)r * D_ + tid]);
      __syncthreads();
      float s_c[8], rs = 0.f;
      for (int j = 0; j < 8; j++){
        int m = j*256+tid; float dot = 0.f;
        for (int k = 0; k < D_; k++) dot += prow[k] * bf2f(Bm[(size_t)m * D_ + k]);
        float d = pnb[r] + lnb[m] - 2.f*dot;
        float s = __expf(ef * d) * cost_c[j];
        s_c[j] = s; rs += s;
      }
      float tot = blockReduceSum(rs, red);
      float a = curb[r] / (tot + EPS_);
      if (tid == 0) alpha_l[r] = a;
      #pragma unroll
      for (int j = 0; j < 8; j++) colsum_c[j] += s_c[j] * a;
      __syncthreads();
    }
    #pragma unroll
    for (int j = 0; j < 8; j++){
      float cs = colsum_c[j];
      float bw = fminf(cost_c[j] / (cs + EPS_), 1.f);
      bw_c[j] = bw; costnew_c[j] = fmaxf(cost_c[j] - bw*cs, 0.f);
    }
    float contrib = 0.f;
    for (int r = 0; r < N_; r++){
      prow[tid] = bf2f(A[(size_t)r * D_ + tid]);
      __syncthreads();
      float a = alpha_l[r], rbs = 0.f;
      for (int j = 0; j < 8; j++){
        int m = j*256+tid; float dot = 0.f;
        for (int k = 0; k < D_; k++) dot += prow[k] * bf2f(Bm[(size_t)m * D_ + k]);
        float d = pnb[r] + lnb[m] - 2.f*dot;
        float bid = __expf(ef * d) * cost_c[j] * a * bw_c[j];
        rbs += bid; contrib += bid * d;
      }
      float tot = blockReduceSum(rbs, red);
      if (tid == 0) curb[r] = fmaxf(curb[r] - tot, 0.f);
      __syncthreads();
    }
    #pragma unroll
    for (int j = 0; j < 8; j++) costb[j*256+tid] = costnew_c[j];
    float ctot = blockReduceSum(contrib, red);
    if (tid == 0) atomicAdd(out, ctot);
    __syncthreads();
  }
  // ---- fused ef=0 closed-form scalars: exp(0*d)=1 exactly, so
  // sum(bids*d) = Spn*Sv + Sa*Sln - 2*(sum alpha*p).(sum v*l). ----
  float* ab = alpha + (size_t)b * N_;
  float* vb = v + (size_t)b * N_;
  float s = 0.f;
  #pragma unroll
  for (int j = 0; j < 8; j++) s += costb[j*256+tid];
  float Sc = blockReduceSum(s, red);
  float sa = 0.f, spn = 0.f;
  #pragma unroll
  for (int j = 0; j < 8; j++){
    int i = j*256+tid;
    float a = curb[i] / (Sc + EPS_);
    ab[i] = a; sa += a; spn += a * pnb[i];
  }
  float Sa  = blockReduceSum(sa, red);
  float Spn = blockReduceSum(spn, red);
  float sv = 0.f, sln = 0.f;
  #pragma unroll
  for (int j = 0; j < 8; j++){
    int i = j*256+tid;
    float c = costb[j*256+tid];
    float bw = fminf(c / (c * Sa + EPS_), 1.f);
    float vv = c * bw;
    vb[i] = vv; sv += vv; sln += vv * lnb[i];
  }
  float Sv  = blockReduceSum(sv, red);
  float Sln = blockReduceSum(sln, red);
  if (tid == 0){
    scal[b*4+0] = Sa; scal[b*4+1] = Sv; scal[b*4+2] = Spn; scal[b*4+3] = Sln;
  }
}

// P_b = sum_r alpha_r * preds[b][r][:], L_b = sum_m v_m * labels[b][m][:]
__global__ __launch_bounds__(256) void cf_wsum(
    const unsigned short* __restrict__ pabf, const unsigned short* __restrict__ pbbf,
    const float* __restrict__ alpha, const float* __restrict__ v,
    float* __restrict__ PL)
{
  int chunk = blockIdx.x, src = blockIdx.y, b = blockIdx.z, tid = threadIdx.x;
  int g = tid >> 6, c4 = (tid & 63) * 4;
  const unsigned short* X = (src ? pbbf : pabf) + ((size_t)b * N_ + chunk * 64) * D_;
  const float* wv = (src ? v : alpha) + (size_t)b * N_ + chunk * 64;
  __shared__ float wl[64];
  __shared__ float part[4][D_];
  if (tid < 64) wl[tid] = wv[tid];
  __syncthreads();
  f4 acc = (f4)0.f;
  for (int r = g * 16; r < g * 16 + 16; r++){
    uint2 pk = *(const uint2*)&X[(size_t)r * D_ + c4];
    float wr = wl[r];
    acc[0] = fmaf(wr, __uint_as_float(pk.x << 16), acc[0]);
    acc[1] = fmaf(wr, __uint_as_float(pk.x & 0xffff0000u), acc[1]);
    acc[2] = fmaf(wr, __uint_as_float(pk.y << 16), acc[2]);
    acc[3] = fmaf(wr, __uint_as_float(pk.y & 0xffff0000u), acc[3]);
  }
  #pragma unroll
  for (int q = 0; q < 4; q++) part[g][c4 + q] = acc[q];
  __syncthreads();
  float s = part[0][tid] + part[1][tid] + part[2][tid] + part[3][tid];
  atomicAdd(&PL[((size_t)src * B_ + b) * D_ + tid], s);
}

__global__ __launch_bounds__(256) void cf_final(
    const float* __restrict__ PL, const float* __restrict__ scal,
    float* __restrict__ out)
{
  int b = blockIdx.x, tid = threadIdx.x;
  __shared__ float red[256];
  float p = PL[(size_t)b * D_ + tid] * PL[((size_t)B_ + b) * D_ + tid];
  float dot = blockReduceSum(p, red);
  if (tid == 0){
    float Sa = scal[b*4+0], Sv = scal[b*4+1], Spn = scal[b*4+2], Sln = scal[b*4+3];
    atomicAdd(out, Spn * Sv + Sa * Sln - 2.f * dot);
  }
}

extern "C" void kernel_launch(void* const* d_in, const int* in_sizes, int n_in,
                              void* d_out, int out_size, void* d_ws, size_t ws_size,
                              hipStream_t stream)
{
  const float* preds  = (const float*)d_in[0];
  const float* labels = (const float*)d_in[1];
  float* out = (float*)d_out;
  char* ws = (char*)d_ws;
  const size_t BN = (size_t)B_ * N_;
  size_t off = 0;
  float* cost     = (float*)(ws + off); off += BN * 4;
  float* currency = (float*)(ws + off); off += BN * 4;
  float* alpha    = (float*)(ws + off); off += BN * 4;
  float* v        = (float*)(ws + off); off += BN * 4;
  float* pn       = (float*)(ws + off); off += BN * 4;
  float* ln       = (float*)(ws + off); off += BN * 4;
  int*   dmin     = (int*)(ws + off);   off += 256;
  float* scal     = (float*)(ws + off); off += 256;
  float* PL       = (float*)(ws + off); off += (size_t)2 * B_ * D_ * 4;
  unsigned short* pabf = (unsigned short*)(ws + off); off += BN * D_ * 2;
  unsigned short* pbbf = (unsigned short*)(ws + off); off += BN * D_ * 2;

  prep_kernel<<<dim3((unsigned)(BN / 4), 2), 256, 0, stream>>>(
      preds, labels, pabf, pbbf, pn, ln, cost, currency, dmin, PL, scal, out);
  gemm_minmax<<<dim3(8, 16, B_), 256, 0, stream>>>(pabf, pbbf, pn, ln, dmin);
  fb_all<<<dim3(B_), 256, 0, stream>>>(pabf, pbbf, pn, ln, cost, currency, dmin, out,
                                       alpha, v, scal);
  cf_wsum<<<dim3(32, 2, B_), 256, 0, stream>>>(pabf, pbbf, alpha, v, PL);
  cf_final<<<dim3(B_), 256, 0, stream>>>(PL, scal, out);
}